// Round 1
// baseline (813.088 us; speedup 1.0000x reference)
//
#include <hip/hip_runtime.h>

typedef __attribute__((ext_vector_type(8))) short bf16x8;
typedef __attribute__((ext_vector_type(4))) float f32x4;

#define S_LEN 16384
#define EMB   1152
#define NQKV  3456
#define NH    16
#define HD    72

__device__ __forceinline__ unsigned short f2b(float f){
  union { float f; unsigned u; } x; x.f = f;
  unsigned r = x.u + 0x7fffu + ((x.u >> 16) & 1u);
  return (unsigned short)(r >> 16);
}
__device__ __forceinline__ float b2f(unsigned short h){
  union { unsigned u; float f; } x; x.u = ((unsigned)h) << 16; return x.f;
}
__device__ __forceinline__ void glds16(const void* g, void* l){
  __builtin_amdgcn_global_load_lds((const __attribute__((address_space(1))) void*)g,
                                   (__attribute__((address_space(3))) void*)l, 16, 0, 0);
}

// ---------------- prep: hs fp32 -> bf16 ----------------
__global__ void prep_hs(const float* __restrict__ hs, unsigned short* __restrict__ hsb){
  long i = (long)blockIdx.x*256 + threadIdx.x;          // one thread = 8 elems
  const long n8 = (long)S_LEN*EMB/8;
  if (i >= n8) return;
  const float4* p = (const float4*)(hs + i*8);
  float4 a = p[0], b = p[1];
  uint4 o;
  o.x = f2b(a.x) | ((unsigned)f2b(a.y)<<16);
  o.y = f2b(a.z) | ((unsigned)f2b(a.w)<<16);
  o.z = f2b(b.x) | ((unsigned)f2b(b.y)<<16);
  o.w = f2b(b.z) | ((unsigned)f2b(b.w)<<16);
  *(uint4*)(hsb + i*8) = o;
}

// ---------------- prep: weights -> bf16 transposed [N][K]; pack qkv bias ----------------
__global__ void prep_w(const float* __restrict__ Wq, const float* __restrict__ Wk,
                       const float* __restrict__ Wv, const float* __restrict__ Wo,
                       const float* __restrict__ bq, const float* __restrict__ bk,
                       const float* __restrict__ bv,
                       unsigned short* __restrict__ wqkv, unsigned short* __restrict__ wot,
                       float* __restrict__ biasq){
  long i = (long)blockIdx.x*256 + threadIdx.x;          // over 4608*1152, k fastest
  if (i < NQKV)
    biasq[i] = (i < 1152) ? bq[i] : (i < 2304 ? bk[i-1152] : bv[i-2304]);
  if (i >= (long)4608*1152) return;
  int k  = (int)(i % 1152);
  int n  = (int)(i / 1152);
  int sel = n / 1152, nn = n % 1152;
  const float* W = (sel==0)?Wq:(sel==1)?Wk:(sel==2)?Wv:Wo;
  unsigned short v = f2b(W[(long)k*1152 + nn]);
  if (sel < 3) wqkv[(long)n*1152 + k] = v;
  else         wot [(long)nn*1152 + k] = v;
}

// ---------------- GEMM: C[M][N] = A[M][K](bf16) * Bt[N][K]^T + bias ----------------
// 128x128 tile, BK=64, 4 waves, 16x16x32 bf16 MFMA, global_load_lds staging (m97 structure)
template<int OUTF32>
__global__ __launch_bounds__(256) void gemm_bt(
    const unsigned short* __restrict__ A,
    const unsigned short* __restrict__ Bt,
    const float* __restrict__ bias,
    unsigned short* __restrict__ Cb,
    float* __restrict__ Cf,
    int N, int K)
{
  __shared__ unsigned short As[128*64];
  __shared__ unsigned short Bs[128*64];
  int tid = threadIdx.x;
  int lane = tid & 63, wave = tid >> 6;
  int wm = wave >> 1, wn = wave & 1;
  long ar0 = (long)blockIdx.y * 128;
  long bc0 = (long)blockIdx.x * 128;
  const unsigned short* ag = A  + (ar0 + tid/8)*(long)K + (tid&7)*8;
  const unsigned short* bg = Bt + (bc0 + tid/8)*(long)K + (tid&7)*8;
  unsigned short* al = As + tid*8;
  unsigned short* bl = Bs + tid*8;
  f32x4 acc[4][4];
  #pragma unroll
  for (int mi=0;mi<4;mi++)
    #pragma unroll
    for (int ni=0;ni<4;ni++) acc[mi][ni] = (f32x4){0.f,0.f,0.f,0.f};
  int lr = lane & 15, lk = (lane>>4)*8;
  for (int k0=0; k0<K; k0+=64){
    __syncthreads();
    #pragma unroll
    for (int i=0;i<4;i++){
      glds16(ag + (long)i*32*K + k0, al + i*32*64);
      glds16(bg + (long)i*32*K + k0, bl + i*32*64);
    }
    __syncthreads();
    #pragma unroll
    for (int ks=0;ks<2;ks++){
      bf16x8 af[4], bfr[4];
      #pragma unroll
      for (int mi=0;mi<4;mi++) af[mi]  = *(const bf16x8*)&As[(wm*64+mi*16+lr)*64 + ks*32 + lk];
      #pragma unroll
      for (int ni=0;ni<4;ni++) bfr[ni] = *(const bf16x8*)&Bs[(wn*64+ni*16+lr)*64 + ks*32 + lk];
      #pragma unroll
      for (int mi=0;mi<4;mi++)
        #pragma unroll
        for (int ni=0;ni<4;ni++)
          acc[mi][ni] = __builtin_amdgcn_mfma_f32_16x16x32_bf16(af[mi], bfr[ni], acc[mi][ni], 0,0,0);
    }
  }
  int orow = (lane>>4)*4, ocol = lane & 15;
  #pragma unroll
  for (int mi=0;mi<4;mi++){
    long r0 = ar0 + wm*64 + mi*16 + orow;
    #pragma unroll
    for (int ni=0;ni<4;ni++){
      long c = bc0 + wn*64 + ni*16 + ocol;
      float bb = bias[c];
      #pragma unroll
      for (int r=0;r<4;r++){
        float v = acc[mi][ni][r] + bb;
        if (OUTF32) Cf[(r0+r)*(long)N + c] = v;
        else        Cb[(r0+r)*(long)N + c] = f2b(v);
      }
    }
  }
}

// ---------------- RoPE in-place on q,k parts of qkv ----------------
__global__ void rope_k(unsigned short* __restrict__ qkv,
                       const float* __restrict__ cs, const float* __restrict__ sn){
  long i = (long)blockIdx.x*256 + threadIdx.x;
  const long tot = 2L*S_LEN*NH*36;
  if (i >= tot) return;
  int d = (int)(i % 36); long t2 = i/36;
  int h = (int)(t2 % NH); long t3 = t2/NH;
  int s = (int)(t3 % S_LEN); int qk = (int)(t3 / S_LEN);
  long base = (long)s*NQKV + (long)qk*1152 + h*HD;
  float x1 = b2f(qkv[base + d]), x2 = b2f(qkv[base + d + 36]);
  float c1 = cs[(long)s*HD + d], c2 = cs[(long)s*HD + d + 36];
  float s1 = sn[(long)s*HD + d], s2 = sn[(long)s*HD + d + 36];
  qkv[base + d]      = f2b(x1*c1 - x2*s1);
  qkv[base + d + 36] = f2b(x2*c2 + x1*s2);
}

// ---------------- transpose V: qkv v-part -> vt[bh][72][1024] ----------------
__global__ void transpose_v(const unsigned short* __restrict__ qkv, unsigned short* __restrict__ vt){
  __shared__ unsigned short t[64*72];
  int tid = threadIdx.x;
  int kt = blockIdx.x, bh = blockIdx.y;
  int b = bh >> 4, h = bh & 15;
  const unsigned short* src = qkv + ((long)b*1024 + (long)kt*64)*NQKV + 2304 + h*HD;
  #pragma unroll
  for (int i=0;i<3;i++){
    int idx = i*256 + tid;
    if (idx < 576){
      int r = idx/9, c = (idx%9)*8;
      *(uint4*)&t[r*72 + c] = *(const uint4*)&src[(long)r*NQKV + c];
    }
  }
  __syncthreads();
  unsigned short* dst = vt + (long)bh*HD*1024 + (long)kt*64;
  #pragma unroll
  for (int i=0;i<3;i++){
    int idx = i*256 + tid;
    if (idx < 576){
      int d = idx>>3, k8 = (idx&7)*8;
      unsigned short v[8];
      #pragma unroll
      for (int j=0;j<8;j++) v[j] = t[(k8+j)*72 + d];
      uint4 o;
      o.x = v[0] | ((unsigned)v[1]<<16);
      o.y = v[2] | ((unsigned)v[3]<<16);
      o.z = v[4] | ((unsigned)v[5]<<16);
      o.w = v[6] | ((unsigned)v[7]<<16);
      *(uint4*)&dst[(long)d*1024 + k8] = o;
    }
  }
}

// ---------------- flash attention ----------------
// grid (8, 256): x = q-tile of 128 rows, y = (b*16+h). 4 waves x 32 q-rows/wave.
__global__ __launch_bounds__(256) void attn_k(
    const unsigned short* __restrict__ qkv,
    const unsigned short* __restrict__ vt,
    unsigned short* __restrict__ aout)
{
  __shared__ unsigned short Ks[64*72 + 32];   // [key][d], +pad so b128 over-reads stay in-bounds
  __shared__ unsigned short Vts[80*72];       // [d][key], rows 72..79 zeroed
  __shared__ unsigned short Pl[4][32*72];     // per-wave P, row stride 72 (144B, ~conflict-free)
  int tid = threadIdx.x, lane = tid & 63, w = tid >> 6;
  int bh = blockIdx.y; int b = bh >> 4, h = bh & 15;
  int qt = blockIdx.x;
  int lr = lane & 15, g = lane >> 4;

  // zero pads once
  uint4 z4 = make_uint4(0,0,0,0);
  if (tid < 4)  *(uint4*)&Ks[64*72 + tid*8] = z4;
  if (tid < 72) *(uint4*)&Vts[72*72 + tid*8] = z4;

  // Q fragments (held in regs); rows = qt*128 + w*32 + mi*16 + lr
  bf16x8 qf[2][3];
  long sq_base = (long)b*1024 + (long)qt*128 + w*32;
  #pragma unroll
  for (int mi=0;mi<2;mi++){
    long s = sq_base + mi*16 + lr;
    #pragma unroll
    for (int ks=0;ks<3;ks++){
      int d = ks*32 + g*8;
      if (d < HD) qf[mi][ks] = *(const bf16x8*)&qkv[s*NQKV + h*HD + d];
      else        qf[mi][ks] = (bf16x8){0,0,0,0,0,0,0,0};
    }
  }
  f32x4 oacc[2][5];
  #pragma unroll
  for (int mi=0;mi<2;mi++)
    #pragma unroll
    for (int nd=0;nd<5;nd++) oacc[mi][nd] = (f32x4){0.f,0.f,0.f,0.f};
  float mrow[2][4], lsum[2][4];
  #pragma unroll
  for (int mi=0;mi<2;mi++)
    #pragma unroll
    for (int r=0;r<4;r++){ mrow[mi][r] = -1e30f; lsum[mi][r] = 0.f; }

  const float SL = 0.11785113f * 1.44269504f;   // 72^-0.5 * log2(e)
  const unsigned short* vg0 = vt + (long)bh*HD*1024;

  for (int kt=0; kt<16; kt++){
    __syncthreads();
    // stage K tile: 64 keys x 72 dims
    const unsigned short* kg = qkv + ((long)b*1024 + (long)kt*64)*NQKV + 1152 + h*HD;
    const unsigned short* vg = vg0 + (long)kt*64;
    #pragma unroll
    for (int i=0;i<3;i++){
      int idx = i*256 + tid;
      if (idx < 576){
        int r = idx/9, c = (idx%9)*8;
        *(uint4*)&Ks[r*72 + c] = *(const uint4*)&kg[(long)r*NQKV + c];
      }
      if (idx < 576){
        int d = idx>>3, c = (idx&7)*8;
        *(uint4*)&Vts[d*72 + c] = *(const uint4*)&vg[(long)d*1024 + c];
      }
    }
    __syncthreads();

    // QK^T: S[q][key], D padded to 96 (Q-side zeros kill garbage)
    f32x4 sacc[2][4];
    #pragma unroll
    for (int mi=0;mi<2;mi++)
      #pragma unroll
      for (int ni=0;ni<4;ni++) sacc[mi][ni] = (f32x4){0.f,0.f,0.f,0.f};
    #pragma unroll
    for (int ks=0;ks<3;ks++){
      bf16x8 kf[4];
      #pragma unroll
      for (int ni=0;ni<4;ni++) kf[ni] = *(const bf16x8*)&Ks[(ni*16+lr)*72 + ks*32 + g*8];
      #pragma unroll
      for (int mi=0;mi<2;mi++)
        #pragma unroll
        for (int ni=0;ni<4;ni++)
          sacc[mi][ni] = __builtin_amdgcn_mfma_f32_16x16x32_bf16(qf[mi][ks], kf[ni], sacc[mi][ni], 0,0,0);
    }

    // online softmax (raw scores; scale folded into exp2 factor)
    #pragma unroll
    for (int mi=0;mi<2;mi++){
      float tm[4];
      #pragma unroll
      for (int r=0;r<4;r++)
        tm[r] = fmaxf(fmaxf(sacc[mi][0][r], sacc[mi][1][r]), fmaxf(sacc[mi][2][r], sacc[mi][3][r]));
      #pragma unroll
      for (int off=1; off<16; off<<=1)
        #pragma unroll
        for (int r=0;r<4;r++) tm[r] = fmaxf(tm[r], __shfl_xor(tm[r], off));
      #pragma unroll
      for (int r=0;r<4;r++){
        float mn  = fmaxf(mrow[mi][r], tm[r]);
        float corr = __builtin_amdgcn_exp2f((mrow[mi][r] - mn)*SL);
        mrow[mi][r] = mn;
        float rs = 0.f;
        #pragma unroll
        for (int ni=0;ni<4;ni++){
          float pv = __builtin_amdgcn_exp2f((sacc[mi][ni][r] - mn)*SL);
          sacc[mi][ni][r] = pv;   // reuse regs as P
          rs += pv;
        }
        #pragma unroll
        for (int off=1; off<16; off<<=1) rs += __shfl_xor(rs, off);
        lsum[mi][r] = lsum[mi][r]*corr + rs;
        #pragma unroll
        for (int nd=0; nd<5; nd++) oacc[mi][nd][r] *= corr;
      }
    }

    // write P (bf16) to this wave's LDS buffer: row = q-in-tile, col = key
    #pragma unroll
    for (int mi=0;mi<2;mi++)
      #pragma unroll
      for (int ni=0;ni<4;ni++)
        #pragma unroll
        for (int r=0;r<4;r++)
          Pl[w][(mi*16 + g*4 + r)*72 + ni*16 + lr] = f2b(sacc[mi][ni][r]);

    // PV: O[q][d] += P[q][key] * V[key][d]
    #pragma unroll
    for (int ks=0;ks<2;ks++){
      bf16x8 pf[2], vf[5];
      #pragma unroll
      for (int mi=0;mi<2;mi++) pf[mi] = *(const bf16x8*)&Pl[w][(mi*16+lr)*72 + ks*32 + g*8];
      #pragma unroll
      for (int nd=0;nd<5;nd++) vf[nd] = *(const bf16x8*)&Vts[(nd*16+lr)*72 + ks*32 + g*8];
      #pragma unroll
      for (int mi=0;mi<2;mi++)
        #pragma unroll
        for (int nd=0;nd<5;nd++)
          oacc[mi][nd] = __builtin_amdgcn_mfma_f32_16x16x32_bf16(pf[mi], vf[nd], oacc[mi][nd], 0,0,0);
    }
  }

  // epilogue: O /= l, store bf16
  #pragma unroll
  for (int mi=0;mi<2;mi++){
    #pragma unroll
    for (int r=0;r<4;r++){
      float inv = 1.f / lsum[mi][r];
      long s = sq_base + mi*16 + g*4 + r;
      #pragma unroll
      for (int nd=0;nd<5;nd++){
        int d = nd*16 + lr;
        if (d < HD) aout[s*EMB + h*HD + d] = f2b(oacc[mi][nd][r]*inv);
      }
    }
  }
}

extern "C" void kernel_launch(void* const* d_in, const int* in_sizes, int n_in,
                              void* d_out, int out_size, void* d_ws, size_t ws_size,
                              hipStream_t stream){
  const float* hs = (const float*)d_in[0];
  const float* cs = (const float*)d_in[2];
  const float* sn = (const float*)d_in[3];
  const float* Wq = (const float*)d_in[4];
  const float* bq = (const float*)d_in[5];
  const float* Wk = (const float*)d_in[6];
  const float* bk = (const float*)d_in[7];
  const float* Wv = (const float*)d_in[8];
  const float* bv = (const float*)d_in[9];
  const float* Wo = (const float*)d_in[10];
  const float* bo = (const float*)d_in[11];
  float* out = (float*)d_out;

  char* ws = (char*)d_ws;
  size_t off = 0;
  unsigned short* hsb  = (unsigned short*)(ws + off); off += (size_t)S_LEN*EMB*2;   // reused as attn_out
  unsigned short* wqkv = (unsigned short*)(ws + off); off += (size_t)NQKV*EMB*2;
  unsigned short* wot  = (unsigned short*)(ws + off); off += (size_t)EMB*EMB*2;
  float*          biasq= (float*)(ws + off);          off += (size_t)NQKV*4 + 2560;
  unsigned short* qkv  = (unsigned short*)(ws + off); off += (size_t)S_LEN*NQKV*2;
  unsigned short* vt   = (unsigned short*)(ws + off); off += (size_t)256*HD*1024*2;

  prep_hs<<<(S_LEN*EMB/8 + 255)/256, 256, 0, stream>>>(hs, hsb);
  prep_w<<<((long)4608*1152 + 255)/256, 256, 0, stream>>>(Wq, Wk, Wv, Wo, bq, bk, bv, wqkv, wot, biasq);
  gemm_bt<0><<<dim3(NQKV/128, S_LEN/128), 256, 0, stream>>>(hsb, wqkv, biasq, qkv, nullptr, NQKV, EMB);
  rope_k<<<(2L*S_LEN*NH*36 + 255)/256, 256, 0, stream>>>(qkv, cs, sn);
  transpose_v<<<dim3(16, 256), 256, 0, stream>>>(qkv, vt);
  attn_k<<<dim3(8, 256), 256, 0, stream>>>(qkv, vt, hsb);
  gemm_bt<1><<<dim3(EMB/128, S_LEN/128), 256, 0, stream>>>(hsb, wot, bo, nullptr, out, EMB, EMB);
}

// Round 6
// 695.921 us; speedup vs baseline: 1.1684x; 1.1684x over previous
//
#include <hip/hip_runtime.h>

typedef __attribute__((ext_vector_type(8))) short bf16x8;
typedef __attribute__((ext_vector_type(4))) float f32x4;

#define S_LEN 16384
#define EMB   1152
#define NQKV  3456
#define NH    16
#define HD    72

__device__ __forceinline__ unsigned short f2b(float f){
  union { float f; unsigned u; } x; x.f = f;
  unsigned r = x.u + 0x7fffu + ((x.u >> 16) & 1u);
  return (unsigned short)(r >> 16);
}
__device__ __forceinline__ float b2f(unsigned short h){
  union { unsigned u; float f; } x; x.u = ((unsigned)h) << 16; return x.f;
}
__device__ __forceinline__ void glds16(const void* g, void* l){
  __builtin_amdgcn_global_load_lds((const __attribute__((address_space(1))) void*)g,
                                   (__attribute__((address_space(3))) void*)l, 16, 0, 0);
}

// ---------------- prep: hs fp32 -> bf16 (round-1 exact) ----------------
__global__ void prep_hs(const float* __restrict__ hs, unsigned short* __restrict__ hsb){
  long i = (long)blockIdx.x*256 + threadIdx.x;          // one thread = 8 elems
  const long n8 = (long)S_LEN*EMB/8;
  if (i >= n8) return;
  const float4* p = (const float4*)(hs + i*8);
  float4 a = p[0], b = p[1];
  uint4 o;
  o.x = f2b(a.x) | ((unsigned)f2b(a.y)<<16);
  o.y = f2b(a.z) | ((unsigned)f2b(a.w)<<16);
  o.z = f2b(b.x) | ((unsigned)f2b(b.y)<<16);
  o.w = f2b(b.z) | ((unsigned)f2b(b.w)<<16);
  *(uint4*)(hsb + i*8) = o;
}

// ---------------- prep: weights -> bf16 transposed [N][K] (round-1 exact) ----------------
__global__ void prep_w(const float* __restrict__ Wq, const float* __restrict__ Wk,
                       const float* __restrict__ Wv, const float* __restrict__ Wo,
                       const float* __restrict__ bq, const float* __restrict__ bk,
                       const float* __restrict__ bv,
                       unsigned short* __restrict__ wqkv, unsigned short* __restrict__ wot,
                       float* __restrict__ biasq){
  long i = (long)blockIdx.x*256 + threadIdx.x;          // over 4608*1152, k fastest
  if (i < NQKV)
    biasq[i] = (i < 1152) ? bq[i] : (i < 2304 ? bk[i-1152] : bv[i-2304]);
  if (i >= (long)4608*1152) return;
  int k  = (int)(i % 1152);
  int n  = (int)(i / 1152);
  int sel = n / 1152, nn = n % 1152;
  const float* W = (sel==0)?Wq:(sel==1)?Wk:(sel==2)?Wv:Wo;
  unsigned short v = f2b(W[(long)k*1152 + nn]);
  if (sel < 3) wqkv[(long)n*1152 + k] = v;
  else         wot [(long)nn*1152 + k] = v;
}

// ---------------- GEMM: C[M][N] = A[M][K](bf16) * Bt[N][K]^T + bias (round-1 exact) ----------------
template<int OUTF32>
__global__ __launch_bounds__(256) void gemm_bt(
    const unsigned short* __restrict__ A,
    const unsigned short* __restrict__ Bt,
    const float* __restrict__ bias,
    unsigned short* __restrict__ Cb,
    float* __restrict__ Cf,
    int N, int K)
{
  __shared__ unsigned short As[128*64];
  __shared__ unsigned short Bs[128*64];
  int tid = threadIdx.x;
  int lane = tid & 63, wave = tid >> 6;
  int wm = wave >> 1, wn = wave & 1;
  long ar0 = (long)blockIdx.y * 128;
  long bc0 = (long)blockIdx.x * 128;
  const unsigned short* ag = A  + (ar0 + tid/8)*(long)K + (tid&7)*8;
  const unsigned short* bg = Bt + (bc0 + tid/8)*(long)K + (tid&7)*8;
  unsigned short* al = As + tid*8;
  unsigned short* bl = Bs + tid*8;
  f32x4 acc[4][4];
  #pragma unroll
  for (int mi=0;mi<4;mi++)
    #pragma unroll
    for (int ni=0;ni<4;ni++) acc[mi][ni] = (f32x4){0.f,0.f,0.f,0.f};
  int lr = lane & 15, lk = (lane>>4)*8;
  for (int k0=0; k0<K; k0+=64){
    __syncthreads();
    #pragma unroll
    for (int i=0;i<4;i++){
      glds16(ag + (long)i*32*K + k0, al + i*32*64);
      glds16(bg + (long)i*32*K + k0, bl + i*32*64);
    }
    __syncthreads();
    #pragma unroll
    for (int ks=0;ks<2;ks++){
      bf16x8 af[4], bfr[4];
      #pragma unroll
      for (int mi=0;mi<4;mi++) af[mi]  = *(const bf16x8*)&As[(wm*64+mi*16+lr)*64 + ks*32 + lk];
      #pragma unroll
      for (int ni=0;ni<4;ni++) bfr[ni] = *(const bf16x8*)&Bs[(wn*64+ni*16+lr)*64 + ks*32 + lk];
      #pragma unroll
      for (int mi=0;mi<4;mi++)
        #pragma unroll
        for (int ni=0;ni<4;ni++)
          acc[mi][ni] = __builtin_amdgcn_mfma_f32_16x16x32_bf16(af[mi], bfr[ni], acc[mi][ni], 0,0,0);
    }
  }
  int orow = (lane>>4)*4, ocol = lane & 15;
  #pragma unroll
  for (int mi=0;mi<4;mi++){
    long r0 = ar0 + wm*64 + mi*16 + orow;
    #pragma unroll
    for (int ni=0;ni<4;ni++){
      long c = bc0 + wn*64 + ni*16 + ocol;
      float bb = bias[c];
      #pragma unroll
      for (int r=0;r<4;r++){
        float v = acc[mi][ni][r] + bb;
        if (OUTF32) Cf[(r0+r)*(long)N + c] = v;
        else        Cb[(r0+r)*(long)N + c] = f2b(v);
      }
    }
  }
}

// ---------------- RoPE in-place on q,k parts of qkv (round-1 exact) ----------------
__global__ void rope_k(unsigned short* __restrict__ qkv,
                       const float* __restrict__ cs, const float* __restrict__ sn){
  long i = (long)blockIdx.x*256 + threadIdx.x;
  const long tot = 2L*S_LEN*NH*36;
  if (i >= tot) return;
  int d = (int)(i % 36); long t2 = i/36;
  int h = (int)(t2 % NH); long t3 = t2/NH;
  int s = (int)(t3 % S_LEN); int qk = (int)(t3 / S_LEN);
  long base = (long)s*NQKV + (long)qk*1152 + h*HD;
  float x1 = b2f(qkv[base + d]), x2 = b2f(qkv[base + d + 36]);
  float c1 = cs[(long)s*HD + d], c2 = cs[(long)s*HD + d + 36];
  float s1 = sn[(long)s*HD + d], s2 = sn[(long)s*HD + d + 36];
  qkv[base + d]      = f2b(x1*c1 - x2*s1);
  qkv[base + d + 36] = f2b(x2*c2 + x1*s2);
}

// ---------------- transpose V: qkv v-part -> vt[bh][72][1024] (round-1 exact) ----------------
__global__ void transpose_v(const unsigned short* __restrict__ qkv, unsigned short* __restrict__ vt){
  __shared__ unsigned short t[64*72];
  int tid = threadIdx.x;
  int kt = blockIdx.x, bh = blockIdx.y;
  int b = bh >> 4, h = bh & 15;
  const unsigned short* src = qkv + ((long)b*1024 + (long)kt*64)*NQKV + 2304 + h*HD;
  #pragma unroll
  for (int i=0;i<3;i++){
    int idx = i*256 + tid;
    if (idx < 576){
      int r = idx/9, c = (idx%9)*8;
      *(uint4*)&t[r*72 + c] = *(const uint4*)&src[(long)r*NQKV + c];
    }
  }
  __syncthreads();
  unsigned short* dst = vt + (long)bh*HD*1024 + (long)kt*64;
  #pragma unroll
  for (int i=0;i<3;i++){
    int idx = i*256 + tid;
    if (idx < 576){
      int d = idx>>3, k8 = (idx&7)*8;
      unsigned short v[8];
      #pragma unroll
      for (int j=0;j<8;j++) v[j] = t[(k8+j)*72 + d];
      uint4 o;
      o.x = v[0] | ((unsigned)v[1]<<16);
      o.y = v[2] | ((unsigned)v[3]<<16);
      o.z = v[4] | ((unsigned)v[5]<<16);
      o.w = v[6] | ((unsigned)v[7]<<16);
      *(uint4*)&dst[(long)d*1024 + k8] = o;
    }
  }
}

// ---------------- flash attention v3: swapped QK^T (16x16x32 only), P via per-wave LDS ----
// grid 2048 x 512thr: 8 waves x 16 q = 128 q/block; one (b,h) per 8 blocks; KV tile = 64 keys.
// S^T = mfma(K_tile, Q): lane owns q = lane&15; keys spread over regs+lane groups.
__global__ __launch_bounds__(512, 1) void attn3_k(
    const unsigned short* __restrict__ qkv,
    const unsigned short* __restrict__ vt,
    unsigned short* __restrict__ aout)
{
  __shared__ unsigned short Ks[64*72 + 32];   // [key][72d], +pad for D=96 over-reads
  __shared__ unsigned short Vts[80*72];       // [d][64key], rows 72..79 zeroed
  __shared__ unsigned short Pt[8][16*72];     // per-wave P[q][64key], stride 72
  int tid = threadIdx.x, lane = tid & 63, w = tid >> 6;
  int G = lane >> 4, l15 = lane & 15;
  int bid = blockIdx.x;
  int wg = (bid & 7)*256 + (bid >> 3);        // bijective XCD chunking (2048 = 8*256)
  int bh = wg >> 3, qt = wg & 7;
  int b = bh >> 4, h = bh & 15;

  const unsigned short* kgbase = qkv + ((long)b*1024)*NQKV + 1152 + h*HD;
  const unsigned short* vgbase = vt + (long)bh*HD*1024;

  // staging chunks (round-1 layouts): K = 576 uint4 (64key x 9), V = 576 uint4 (72d x 8)
  int key0 = tid/9,        kc0 = (tid%9)*8;
  bool ex  = (tid < 64);
  int ki1  = 512 + tid;
  int key1 = ki1/9,        kc1 = (ki1%9)*8;
  long koff0 = (long)key0*NQKV + kc0;  int kdst0 = key0*72 + kc0;
  long koff1 = (long)key1*NQKV + kc1;  int kdst1 = key1*72 + kc1;
  int vd0 = tid>>3,        vc0 = (tid&7)*8;
  int vi1 = 512 + tid;
  int vd1 = vi1>>3,        vc1 = (vi1&7)*8;
  long voff0 = (long)vd0*1024 + vc0;   int vdst0 = vd0*72 + vc0;
  long voff1 = (long)vd1*1024 + vc1;   int vdst1 = vd1*72 + vc1;

  uint4 pf0, pf1, pf2, pf3;
  #define STAGE_ISSUE(KT) do { \
    const unsigned short* kg_ = kgbase + (long)(KT)*64*NQKV; \
    const unsigned short* vg_ = vgbase + (KT)*64; \
    pf0 = *(const uint4*)(kg_ + koff0); \
    pf2 = *(const uint4*)(vg_ + voff0); \
    if (ex){ pf1 = *(const uint4*)(kg_ + koff1); pf3 = *(const uint4*)(vg_ + voff1); } \
  } while(0)
  #define STAGE_WRITE() do { \
    *(uint4*)&Ks[kdst0]  = pf0; \
    *(uint4*)&Vts[vdst0] = pf2; \
    if (ex){ *(uint4*)&Ks[kdst1] = pf1; *(uint4*)&Vts[vdst1] = pf3; } \
  } while(0)

  // zero pads once: Ks tail, Vts rows 72..79
  const uint4 z4 = make_uint4(0,0,0,0);
  if (tid < 4)  *(uint4*)&Ks[64*72 + tid*8] = z4;
  if (tid < 72) *(uint4*)&Vts[72*72 + tid*8] = z4;

  // Q B-operand fragments: lane supplies Q[q = sq0+l15][d = ds*32 + 8G + j]
  long sq0 = (long)b*1024 + qt*128 + w*16;
  const unsigned short* qrow = qkv + (sq0 + l15)*NQKV + h*HD;
  bf16x8 qf[3];
  #pragma unroll
  for (int ds=0; ds<3; ds++){
    int d0 = ds*32 + 8*G;
    if (d0 <= 64) qf[ds] = *(const bf16x8*)(qrow + d0);
    else          qf[ds] = (bf16x8){0,0,0,0,0,0,0,0};
  }

  f32x4 oacc[5];   // O[q = 4G + r][d = nd*16 + l15]
  #pragma unroll
  for (int nd=0; nd<5; nd++) oacc[nd] = (f32x4){0.f,0.f,0.f,0.f};
  float m = -1e30f, lsum = 0.f;
  const float SL = 0.11785113f * 1.44269504f;   // 72^-0.5 * log2(e)

  STAGE_ISSUE(0);
  STAGE_WRITE();
  __syncthreads();

  unsigned short* pw = Pt[w];

  for (int kt=0; kt<16; kt++){
    if (kt < 15) STAGE_ISSUE(kt+1);   // T14: next tile's loads in flight under compute

    // ---- QK^T: S^T[key][q]; sacc[ni][r] = S[q=l15][key = ni*16 + 4G + r] ----
    f32x4 sacc[4];
    #pragma unroll
    for (int ni=0; ni<4; ni++) sacc[ni] = (f32x4){0.f,0.f,0.f,0.f};
    #pragma unroll
    for (int ds=0; ds<3; ds++){
      #pragma unroll
      for (int ni=0; ni<4; ni++){
        bf16x8 kf = *(const bf16x8*)&Ks[(ni*16 + l15)*72 + ds*32 + 8*G];
        sacc[ni] = __builtin_amdgcn_mfma_f32_16x16x32_bf16(kf, qf[ds], sacc[ni], 0,0,0);
      }
    }

    // ---- online softmax: lane-local 16 regs + 2 shuffles ----
    float tm = -1e30f;
    #pragma unroll
    for (int ni=0; ni<4; ni++)
      #pragma unroll
      for (int r=0; r<4; r++) tm = fmaxf(tm, sacc[ni][r]);
    tm = fmaxf(tm, __shfl_xor(tm, 16));
    tm = fmaxf(tm, __shfl_xor(tm, 32));
    float mn = fmaxf(m, tm);
    float corr = __builtin_amdgcn_exp2f((m - mn)*SL);
    m = mn; lsum *= corr;
    float msl = m * SL;
    float rs = 0.f;
    #pragma unroll
    for (int ni=0; ni<4; ni++)
      #pragma unroll
      for (int r=0; r<4; r++){
        float p = __builtin_amdgcn_exp2f(__builtin_fmaf(sacc[ni][r], SL, -msl));
        sacc[ni][r] = p; rs += p;
      }
    rs += __shfl_xor(rs, 16);
    rs += __shfl_xor(rs, 32);
    lsum += rs;

    // ---- write P to per-wave LDS: Pt[q = l15][key = ni*16 + 4G + r] ----
    #pragma unroll
    for (int ni=0; ni<4; ni++){
      unsigned u0 = (unsigned)f2b(sacc[ni][0]) | ((unsigned)f2b(sacc[ni][1])<<16);
      unsigned u1 = (unsigned)f2b(sacc[ni][2]) | ((unsigned)f2b(sacc[ni][3])<<16);
      *(unsigned*)&pw[l15*72 + ni*16 + 4*G]     = u0;
      *(unsigned*)&pw[l15*72 + ni*16 + 4*G + 2] = u1;
    }

    // ---- rescale O by corr of its own q-rows (q = 4G + r, state lives on lane q) ----
    float c0 = __shfl(corr, 4*G + 0);
    float c1 = __shfl(corr, 4*G + 1);
    float c2 = __shfl(corr, 4*G + 2);
    float c3 = __shfl(corr, 4*G + 3);
    #pragma unroll
    for (int nd=0; nd<5; nd++){
      oacc[nd][0] *= c0; oacc[nd][1] *= c1; oacc[nd][2] *= c2; oacc[nd][3] *= c3;
    }

    // ---- PV: O[q][d] += P[q][key] * V[key][d] (round-1 form) ----
    #pragma unroll
    for (int ks=0; ks<2; ks++){
      bf16x8 pA = *(const bf16x8*)&pw[l15*72 + ks*32 + 8*G];
      #pragma unroll
      for (int nd=0; nd<5; nd++){
        bf16x8 vf = *(const bf16x8*)&Vts[(nd*16 + l15)*72 + ks*32 + 8*G];
        oacc[nd] = __builtin_amdgcn_mfma_f32_16x16x32_bf16(pA, vf, oacc[nd], 0,0,0);
      }
    }

    if (kt < 15){
      __syncthreads();
      STAGE_WRITE();
      __syncthreads();
    }
  }

  // ---- epilogue ----
  float inv = 1.f / lsum;
  float i0 = __shfl(inv, 4*G + 0);
  float i1 = __shfl(inv, 4*G + 1);
  float i2 = __shfl(inv, 4*G + 2);
  float i3 = __shfl(inv, 4*G + 3);
  #pragma unroll
  for (int nd=0; nd<5; nd++){
    int d = nd*16 + l15;
    if (d < HD){
      long base = (sq0 + 4*G)*EMB + h*HD + d;
      aout[base        ] = f2b(oacc[nd][0]*i0);
      aout[base +   EMB] = f2b(oacc[nd][1]*i1);
      aout[base + 2*EMB] = f2b(oacc[nd][2]*i2);
      aout[base + 3*EMB] = f2b(oacc[nd][3]*i3);
    }
  }
  #undef STAGE_ISSUE
  #undef STAGE_WRITE
}

extern "C" void kernel_launch(void* const* d_in, const int* in_sizes, int n_in,
                              void* d_out, int out_size, void* d_ws, size_t ws_size,
                              hipStream_t stream){
  const float* hs = (const float*)d_in[0];
  const float* cs = (const float*)d_in[2];
  const float* sn = (const float*)d_in[3];
  const float* Wq = (const float*)d_in[4];
  const float* bq = (const float*)d_in[5];
  const float* Wk = (const float*)d_in[6];
  const float* bk = (const float*)d_in[7];
  const float* Wv = (const float*)d_in[8];
  const float* bv = (const float*)d_in[9];
  const float* Wo = (const float*)d_in[10];
  const float* bo = (const float*)d_in[11];
  float* out = (float*)d_out;

  char* ws = (char*)d_ws;
  size_t off = 0;
  unsigned short* hsb  = (unsigned short*)(ws + off); off += (size_t)S_LEN*EMB*2;   // reused as attn_out
  unsigned short* wqkv = (unsigned short*)(ws + off); off += (size_t)NQKV*EMB*2;
  unsigned short* wot  = (unsigned short*)(ws + off); off += (size_t)EMB*EMB*2;
  float*          biasq= (float*)(ws + off);          off += (size_t)NQKV*4 + 2560;
  unsigned short* qkv  = (unsigned short*)(ws + off); off += (size_t)S_LEN*NQKV*2;
  unsigned short* vt   = (unsigned short*)(ws + off); off += (size_t)256*HD*1024*2;

  prep_hs<<<(S_LEN*EMB/8 + 255)/256, 256, 0, stream>>>(hs, hsb);
  prep_w<<<((long)4608*1152 + 255)/256, 256, 0, stream>>>(Wq, Wk, Wv, Wo, bq, bk, bv, wqkv, wot, biasq);
  gemm_bt<0><<<dim3(NQKV/128, S_LEN/128), 256, 0, stream>>>(hsb, wqkv, biasq, qkv, nullptr, NQKV, EMB);
  rope_k<<<(2L*S_LEN*NH*36 + 255)/256, 256, 0, stream>>>(qkv, cs, sn);
  transpose_v<<<dim3(16, 256), 256, 0, stream>>>(qkv, vt);
  attn3_k<<<2048, 512, 0, stream>>>(qkv, vt, hsb);
  gemm_bt<1><<<dim3(EMB/128, S_LEN/128), 256, 0, stream>>>(hsb, wot, bo, nullptr, out, EMB, EMB);
}

// Round 8
// 614.241 us; speedup vs baseline: 1.3237x; 1.1330x over previous
//
#include <hip/hip_runtime.h>

typedef __attribute__((ext_vector_type(8))) short bf16x8;
typedef __attribute__((ext_vector_type(4))) float f32x4;

#define S_LEN 16384
#define EMB   1152
#define NQKV  3456
#define NH    16
#define HD    72

__device__ __forceinline__ unsigned short f2b(float f){
  union { float f; unsigned u; } x; x.f = f;
  unsigned r = x.u + 0x7fffu + ((x.u >> 16) & 1u);
  return (unsigned short)(r >> 16);
}
__device__ __forceinline__ float b2f(unsigned short h){
  union { unsigned u; float f; } x; x.u = ((unsigned)h) << 16; return x.f;
}
__device__ __forceinline__ void glds16(const void* g, void* l){
  __builtin_amdgcn_global_load_lds((const __attribute__((address_space(1))) void*)g,
                                   (__attribute__((address_space(3))) void*)l, 16, 0, 0);
}

// ---------------- prep: hs fp32 -> bf16 (round-1 exact) ----------------
__global__ void prep_hs(const float* __restrict__ hs, unsigned short* __restrict__ hsb){
  long i = (long)blockIdx.x*256 + threadIdx.x;          // one thread = 8 elems
  const long n8 = (long)S_LEN*EMB/8;
  if (i >= n8) return;
  const float4* p = (const float4*)(hs + i*8);
  float4 a = p[0], b = p[1];
  uint4 o;
  o.x = f2b(a.x) | ((unsigned)f2b(a.y)<<16);
  o.y = f2b(a.z) | ((unsigned)f2b(a.w)<<16);
  o.z = f2b(b.x) | ((unsigned)f2b(b.y)<<16);
  o.w = f2b(b.z) | ((unsigned)f2b(b.w)<<16);
  *(uint4*)(hsb + i*8) = o;
}

// ---------------- prep: weights -> bf16 transposed [N][K] (round-1 exact) ----------------
__global__ void prep_w(const float* __restrict__ Wq, const float* __restrict__ Wk,
                       const float* __restrict__ Wv, const float* __restrict__ Wo,
                       const float* __restrict__ bq, const float* __restrict__ bk,
                       const float* __restrict__ bv,
                       unsigned short* __restrict__ wqkv, unsigned short* __restrict__ wot,
                       float* __restrict__ biasq){
  long i = (long)blockIdx.x*256 + threadIdx.x;          // over 4608*1152, k fastest
  if (i < NQKV)
    biasq[i] = (i < 1152) ? bq[i] : (i < 2304 ? bk[i-1152] : bv[i-2304]);
  if (i >= (long)4608*1152) return;
  int k  = (int)(i % 1152);
  int n  = (int)(i / 1152);
  int sel = n / 1152, nn = n % 1152;
  const float* W = (sel==0)?Wq:(sel==1)?Wk:(sel==2)?Wv:Wo;
  unsigned short v = f2b(W[(long)k*1152 + nn]);
  if (sel < 3) wqkv[(long)n*1152 + k] = v;
  else         wot [(long)nn*1152 + k] = v;
}

// ---------------- GEMM v2: 256x128 tile, BK=64, 3-buf depth-2 counted-vmcnt pipeline ----
// C[M][N] = A[M][K] * Bt[N][K]^T + bias. 512 thr = 8 waves (4x2), 64x64 C per wave.
// LDS chunk-XOR swizzle (chunk ^= row&7): linear glds dest + pre-permuted GLOBAL src,
// same XOR on ds_read side (rule #21). Counted s_waitcnt vmcnt(6) — never 0 mid-loop.
template<int OUTF32>
__global__ __launch_bounds__(512, 2) void gemm8(
    const unsigned short* __restrict__ A,
    const unsigned short* __restrict__ Bt,
    const float* __restrict__ bias,
    unsigned short* __restrict__ Cb,
    float* __restrict__ Cf,
    int N, int K, int NXT)
{
  __shared__ unsigned short lds[3*24576];   // 3 bufs x (A 256x64 + B 128x64) = 144 KB
  const int BUFE = 24576;
  int tid = threadIdx.x, lane = tid & 63, wave = tid >> 6;
  int wm = wave >> 1, wn = wave & 1;        // 4 x 2 waves
  int lr = lane & 15, hi = lane >> 4, rx = lr & 7;

  // T1 bijective XCD remap (gridDim %8 == 0 for both call sites)
  int nblk = gridDim.x, bid = blockIdx.x;
  int cpx = nblk >> 3;
  int swz = (bid & 7)*cpx + (bid >> 3);
  long ar0 = (long)(swz / NXT) * 256;
  long bc0 = (long)(swz % NXT) * 128;

  // staging: 6 glds16/thread/K-tile. flat f = i*512+tid; f<2048: A, else B.
  // LDS dest linear (f*8 elems); global src chunk = cL ^ (row&7).
  const unsigned short* srcp[6];
  int dsto[6];
  #pragma unroll
  for (int i=0;i<6;i++){
    int f = i*512 + tid;
    dsto[i] = f*8;
    if (i < 4){
      int row = f >> 3, cL = f & 7;
      srcp[i] = A + (ar0 + row)*(long)K + (cL ^ (row & 7))*8;
    } else {
      int fb = f - 2048;
      int row = fb >> 3, cL = fb & 7;
      srcp[i] = Bt + (bc0 + row)*(long)K + (cL ^ (row & 7))*8;
    }
  }

  // fragment LDS offsets (elems), chunk = (ks*4 + hi) ^ (row&7), row&7 == lr&7
  int aoff[4][2], boff[4][2];
  #pragma unroll
  for (int mi=0;mi<4;mi++)
    #pragma unroll
    for (int ks=0;ks<2;ks++)
      aoff[mi][ks] = (wm*64 + mi*16 + lr)*64 + (((ks*4 + hi) ^ rx)*8);
  #pragma unroll
  for (int ni=0;ni<4;ni++)
    #pragma unroll
    for (int ks=0;ks<2;ks++)
      boff[ni][ks] = 16384 + (wn*64 + ni*16 + lr)*64 + (((ks*4 + hi) ^ rx)*8);

  f32x4 acc[4][4];
  #pragma unroll
  for (int mi=0;mi<4;mi++)
    #pragma unroll
    for (int ni=0;ni<4;ni++) acc[mi][ni] = (f32x4){0.f,0.f,0.f,0.f};

  const int nT = K >> 6;
  auto STG = [&](int T){
    unsigned short* lb_ = lds + (T % 3)*BUFE;
    long k0_ = (long)T * 64;
    #pragma unroll
    for (int i=0;i<6;i++) glds16(srcp[i] + k0_, lb_ + dsto[i]);
  };

  // prologue: stage tiles 0,1; wait tile0 (allow tile1's 6 in flight)
  STG(0); STG(1);
  asm volatile("s_waitcnt vmcnt(6)" ::: "memory");
  __builtin_amdgcn_s_barrier();

  for (int t=0; t<nT; ++t){
    if (t+2 < nT) STG(t+2);               // prefetch depth 2, overlaps compute
    const unsigned short* lb = lds + (t % 3)*BUFE;
    #pragma unroll
    for (int ks=0;ks<2;ks++){
      bf16x8 af[4], bfv[4];
      #pragma unroll
      for (int mi=0;mi<4;mi++) af[mi]  = *(const bf16x8*)(lb + aoff[mi][ks]);
      #pragma unroll
      for (int ni=0;ni<4;ni++) bfv[ni] = *(const bf16x8*)(lb + boff[ni][ks]);
      #pragma unroll
      for (int mi=0;mi<4;mi++)
        #pragma unroll
        for (int ni=0;ni<4;ni++)
          acc[mi][ni] = __builtin_amdgcn_mfma_f32_16x16x32_bf16(af[mi], bfv[ni], acc[mi][ni], 0,0,0);
    }
    if (t+1 < nT){
      // need tile t+1 complete; allow only tile t+2's loads (if staged) outstanding
      if (t+2 < nT) asm volatile("s_waitcnt vmcnt(6)" ::: "memory");
      else          asm volatile("s_waitcnt vmcnt(0)" ::: "memory");
      __builtin_amdgcn_s_barrier();
    }
  }

  // epilogue (round-1-validated C/D mapping)
  int orow = hi*4, ocol = lr;
  #pragma unroll
  for (int mi=0;mi<4;mi++){
    long r0 = ar0 + wm*64 + mi*16 + orow;
    #pragma unroll
    for (int ni=0;ni<4;ni++){
      long c = bc0 + wn*64 + ni*16 + ocol;
      float bb = bias[c];
      #pragma unroll
      for (int r=0;r<4;r++){
        float v = acc[mi][ni][r] + bb;
        if (OUTF32) Cf[(r0+r)*(long)N + c] = v;
        else        Cb[(r0+r)*(long)N + c] = f2b(v);
      }
    }
  }
}

// ---------------- RoPE in-place on q,k parts of qkv (round-1 exact) ----------------
__global__ void rope_k(unsigned short* __restrict__ qkv,
                       const float* __restrict__ cs, const float* __restrict__ sn){
  long i = (long)blockIdx.x*256 + threadIdx.x;
  const long tot = 2L*S_LEN*NH*36;
  if (i >= tot) return;
  int d = (int)(i % 36); long t2 = i/36;
  int h = (int)(t2 % NH); long t3 = t2/NH;
  int s = (int)(t3 % S_LEN); int qk = (int)(t3 / S_LEN);
  long base = (long)s*NQKV + (long)qk*1152 + h*HD;
  float x1 = b2f(qkv[base + d]), x2 = b2f(qkv[base + d + 36]);
  float c1 = cs[(long)s*HD + d], c2 = cs[(long)s*HD + d + 36];
  float s1 = sn[(long)s*HD + d], s2 = sn[(long)s*HD + d + 36];
  qkv[base + d]      = f2b(x1*c1 - x2*s1);
  qkv[base + d + 36] = f2b(x2*c2 + x1*s2);
}

// ---------------- transpose V: qkv v-part -> vt[bh][72][1024] (round-1 exact) ----------------
__global__ void transpose_v(const unsigned short* __restrict__ qkv, unsigned short* __restrict__ vt){
  __shared__ unsigned short t[64*72];
  int tid = threadIdx.x;
  int kt = blockIdx.x, bh = blockIdx.y;
  int b = bh >> 4, h = bh & 15;
  const unsigned short* src = qkv + ((long)b*1024 + (long)kt*64)*NQKV + 2304 + h*HD;
  #pragma unroll
  for (int i=0;i<3;i++){
    int idx = i*256 + tid;
    if (idx < 576){
      int r = idx/9, c = (idx%9)*8;
      *(uint4*)&t[r*72 + c] = *(const uint4*)&src[(long)r*NQKV + c];
    }
  }
  __syncthreads();
  unsigned short* dst = vt + (long)bh*HD*1024 + (long)kt*64;
  #pragma unroll
  for (int i=0;i<3;i++){
    int idx = i*256 + tid;
    if (idx < 576){
      int d = idx>>3, k8 = (idx&7)*8;
      unsigned short v[8];
      #pragma unroll
      for (int j=0;j<8;j++) v[j] = t[(k8+j)*72 + d];
      uint4 o;
      o.x = v[0] | ((unsigned)v[1]<<16);
      o.y = v[2] | ((unsigned)v[3]<<16);
      o.z = v[4] | ((unsigned)v[5]<<16);
      o.w = v[6] | ((unsigned)v[7]<<16);
      *(uint4*)&dst[(long)d*1024 + k8] = o;
    }
  }
}

// ---------------- flash attention v3 (round-6 exact, passing) ----------------
__global__ __launch_bounds__(512, 1) void attn3_k(
    const unsigned short* __restrict__ qkv,
    const unsigned short* __restrict__ vt,
    unsigned short* __restrict__ aout)
{
  __shared__ unsigned short Ks[64*72 + 32];
  __shared__ unsigned short Vts[80*72];
  __shared__ unsigned short Pt[8][16*72];
  int tid = threadIdx.x, lane = tid & 63, w = tid >> 6;
  int G = lane >> 4, l15 = lane & 15;
  int bid = blockIdx.x;
  int wg = (bid & 7)*256 + (bid >> 3);
  int bh = wg >> 3, qt = wg & 7;
  int b = bh >> 4, h = bh & 15;

  const unsigned short* kgbase = qkv + ((long)b*1024)*NQKV + 1152 + h*HD;
  const unsigned short* vgbase = vt + (long)bh*HD*1024;

  int key0 = tid/9,        kc0 = (tid%9)*8;
  bool ex  = (tid < 64);
  int ki1  = 512 + tid;
  int key1 = ki1/9,        kc1 = (ki1%9)*8;
  long koff0 = (long)key0*NQKV + kc0;  int kdst0 = key0*72 + kc0;
  long koff1 = (long)key1*NQKV + kc1;  int kdst1 = key1*72 + kc1;
  int vd0 = tid>>3,        vc0 = (tid&7)*8;
  int vi1 = 512 + tid;
  int vd1 = vi1>>3,        vc1 = (vi1&7)*8;
  long voff0 = (long)vd0*1024 + vc0;   int vdst0 = vd0*72 + vc0;
  long voff1 = (long)vd1*1024 + vc1;   int vdst1 = vd1*72 + vc1;

  uint4 pf0, pf1, pf2, pf3;
  #define STAGE_ISSUE(KT) do { \
    const unsigned short* kg_ = kgbase + (long)(KT)*64*NQKV; \
    const unsigned short* vg_ = vgbase + (KT)*64; \
    pf0 = *(const uint4*)(kg_ + koff0); \
    pf2 = *(const uint4*)(vg_ + voff0); \
    if (ex){ pf1 = *(const uint4*)(kg_ + koff1); pf3 = *(const uint4*)(vg_ + voff1); } \
  } while(0)
  #define STAGE_WRITE() do { \
    *(uint4*)&Ks[kdst0]  = pf0; \
    *(uint4*)&Vts[vdst0] = pf2; \
    if (ex){ *(uint4*)&Ks[kdst1] = pf1; *(uint4*)&Vts[vdst1] = pf3; } \
  } while(0)

  const uint4 z4 = make_uint4(0,0,0,0);
  if (tid < 4)  *(uint4*)&Ks[64*72 + tid*8] = z4;
  if (tid < 72) *(uint4*)&Vts[72*72 + tid*8] = z4;

  long sq0 = (long)b*1024 + qt*128 + w*16;
  const unsigned short* qrow = qkv + (sq0 + l15)*NQKV + h*HD;
  bf16x8 qf[3];
  #pragma unroll
  for (int ds=0; ds<3; ds++){
    int d0 = ds*32 + 8*G;
    if (d0 <= 64) qf[ds] = *(const bf16x8*)(qrow + d0);
    else          qf[ds] = (bf16x8){0,0,0,0,0,0,0,0};
  }

  f32x4 oacc[5];
  #pragma unroll
  for (int nd=0; nd<5; nd++) oacc[nd] = (f32x4){0.f,0.f,0.f,0.f};
  float m = -1e30f, lsum = 0.f;
  const float SL = 0.11785113f * 1.44269504f;

  STAGE_ISSUE(0);
  STAGE_WRITE();
  __syncthreads();

  unsigned short* pw = Pt[w];

  for (int kt=0; kt<16; kt++){
    if (kt < 15) STAGE_ISSUE(kt+1);

    f32x4 sacc[4];
    #pragma unroll
    for (int ni=0; ni<4; ni++) sacc[ni] = (f32x4){0.f,0.f,0.f,0.f};
    #pragma unroll
    for (int ds=0; ds<3; ds++){
      #pragma unroll
      for (int ni=0; ni<4; ni++){
        bf16x8 kf = *(const bf16x8*)&Ks[(ni*16 + l15)*72 + ds*32 + 8*G];
        sacc[ni] = __builtin_amdgcn_mfma_f32_16x16x32_bf16(kf, qf[ds], sacc[ni], 0,0,0);
      }
    }

    float tm = -1e30f;
    #pragma unroll
    for (int ni=0; ni<4; ni++)
      #pragma unroll
      for (int r=0; r<4; r++) tm = fmaxf(tm, sacc[ni][r]);
    tm = fmaxf(tm, __shfl_xor(tm, 16));
    tm = fmaxf(tm, __shfl_xor(tm, 32));
    float mn = fmaxf(m, tm);
    float corr = __builtin_amdgcn_exp2f((m - mn)*SL);
    m = mn; lsum *= corr;
    float msl = m * SL;
    float rs = 0.f;
    #pragma unroll
    for (int ni=0; ni<4; ni++)
      #pragma unroll
      for (int r=0; r<4; r++){
        float p = __builtin_amdgcn_exp2f(__builtin_fmaf(sacc[ni][r], SL, -msl));
        sacc[ni][r] = p; rs += p;
      }
    rs += __shfl_xor(rs, 16);
    rs += __shfl_xor(rs, 32);
    lsum += rs;

    #pragma unroll
    for (int ni=0; ni<4; ni++){
      unsigned u0 = (unsigned)f2b(sacc[ni][0]) | ((unsigned)f2b(sacc[ni][1])<<16);
      unsigned u1 = (unsigned)f2b(sacc[ni][2]) | ((unsigned)f2b(sacc[ni][3])<<16);
      *(unsigned*)&pw[l15*72 + ni*16 + 4*G]     = u0;
      *(unsigned*)&pw[l15*72 + ni*16 + 4*G + 2] = u1;
    }

    float c0 = __shfl(corr, 4*G + 0);
    float c1 = __shfl(corr, 4*G + 1);
    float c2 = __shfl(corr, 4*G + 2);
    float c3 = __shfl(corr, 4*G + 3);
    #pragma unroll
    for (int nd=0; nd<5; nd++){
      oacc[nd][0] *= c0; oacc[nd][1] *= c1; oacc[nd][2] *= c2; oacc[nd][3] *= c3;
    }

    #pragma unroll
    for (int ks=0; ks<2; ks++){
      bf16x8 pA = *(const bf16x8*)&pw[l15*72 + ks*32 + 8*G];
      #pragma unroll
      for (int nd=0; nd<5; nd++){
        bf16x8 vf = *(const bf16x8*)&Vts[(nd*16 + l15)*72 + ks*32 + 8*G];
        oacc[nd] = __builtin_amdgcn_mfma_f32_16x16x32_bf16(pA, vf, oacc[nd], 0,0,0);
      }
    }

    if (kt < 15){
      __syncthreads();
      STAGE_WRITE();
      __syncthreads();
    }
  }

  float inv = 1.f / lsum;
  float i0 = __shfl(inv, 4*G + 0);
  float i1 = __shfl(inv, 4*G + 1);
  float i2 = __shfl(inv, 4*G + 2);
  float i3 = __shfl(inv, 4*G + 3);
  #pragma unroll
  for (int nd=0; nd<5; nd++){
    int d = nd*16 + l15;
    if (d < HD){
      long base = (sq0 + 4*G)*EMB + h*HD + d;
      aout[base        ] = f2b(oacc[nd][0]*i0);
      aout[base +   EMB] = f2b(oacc[nd][1]*i1);
      aout[base + 2*EMB] = f2b(oacc[nd][2]*i2);
      aout[base + 3*EMB] = f2b(oacc[nd][3]*i3);
    }
  }
  #undef STAGE_ISSUE
  #undef STAGE_WRITE
}

extern "C" void kernel_launch(void* const* d_in, const int* in_sizes, int n_in,
                              void* d_out, int out_size, void* d_ws, size_t ws_size,
                              hipStream_t stream){
  const float* hs = (const float*)d_in[0];
  const float* cs = (const float*)d_in[2];
  const float* sn = (const float*)d_in[3];
  const float* Wq = (const float*)d_in[4];
  const float* bq = (const float*)d_in[5];
  const float* Wk = (const float*)d_in[6];
  const float* bk = (const float*)d_in[7];
  const float* Wv = (const float*)d_in[8];
  const float* bv = (const float*)d_in[9];
  const float* Wo = (const float*)d_in[10];
  const float* bo = (const float*)d_in[11];
  float* out = (float*)d_out;

  char* ws = (char*)d_ws;
  size_t off = 0;
  unsigned short* hsb  = (unsigned short*)(ws + off); off += (size_t)S_LEN*EMB*2;   // reused as attn_out
  unsigned short* wqkv = (unsigned short*)(ws + off); off += (size_t)NQKV*EMB*2;
  unsigned short* wot  = (unsigned short*)(ws + off); off += (size_t)EMB*EMB*2;
  float*          biasq= (float*)(ws + off);          off += (size_t)NQKV*4 + 2560;
  unsigned short* qkv  = (unsigned short*)(ws + off); off += (size_t)S_LEN*NQKV*2;
  unsigned short* vt   = (unsigned short*)(ws + off); off += (size_t)256*HD*1024*2;

  prep_hs<<<(S_LEN*EMB/8 + 255)/256, 256, 0, stream>>>(hs, hsb);
  prep_w<<<((long)4608*1152 + 255)/256, 256, 0, stream>>>(Wq, Wk, Wv, Wo, bq, bk, bv, wqkv, wot, biasq);
  gemm8<0><<<dim3((NQKV/128)*(S_LEN/256)), 512, 0, stream>>>(hsb, wqkv, biasq, qkv, nullptr, NQKV, EMB, NQKV/128);
  rope_k<<<(2L*S_LEN*NH*36 + 255)/256, 256, 0, stream>>>(qkv, cs, sn);
  transpose_v<<<dim3(16, 256), 256, 0, stream>>>(qkv, vt);
  attn3_k<<<2048, 512, 0, stream>>>(qkv, vt, hsb);
  gemm8<1><<<dim3((EMB/128)*(S_LEN/256)), 512, 0, stream>>>(hsb, wot, bo, nullptr, out, EMB, EMB, EMB/128);
}